// Round 4
// baseline (73.652 us; speedup 1.0000x reference)
//
#include <hip/hip_runtime.h>
#include <math.h>

#define BATCH 4096
#define NROWS (2 * BATCH)      // 8192
#define D 128
#define DX 512
#define NBLK 64                // 8192 / 128 tile blocks per dim
#define SEG 4                  // column-tiles per block strip
#define NSEG 16                // 64 / SEG

// sqrt(2*log2(e)) — both Gram operands carry this, so dot == log2(exp(sim))
#define SCALE 1.698644f

// ws float offsets (every slot that is read is written every call; no atomics)
#define WS_RP     0                          // [64][16][128] row partials
#define WS_CP     131072                     // [c][r][wave][128] col partials
#define WS_RECONP 2228224                    // [1024]
#define WS_ZRECP  2229248                    // [256]
#define WS_POSP   2229504                    // [256]
#define WS_LSEP   2229760                    // [64]
#define WS_NBF    2229824                    // __bf16[8192][128] (16B aligned)

typedef __bf16 bf16x8 __attribute__((ext_vector_type(8)));
typedef __bf16 bf16x2 __attribute__((ext_vector_type(2)));
typedef float  f32x16 __attribute__((ext_vector_type(16)));
typedef unsigned int u32;

__device__ __forceinline__ void gload_lds16(const void* g, void* l) {
    __builtin_amdgcn_global_load_lds(
        (const __attribute__((address_space(1))) u32*)g,
        (__attribute__((address_space(3))) u32*)l, 16, 0, 0);
}

__device__ __forceinline__ float wave_reduce(float v) {
    #pragma unroll
    for (int o = 32; o > 0; o >>= 1) v += __shfl_xor(v, o);
    return v;
}

// one wave per (i, i+B) pair: norms, scaled-bf16 rows, zrecon & positives partials
__global__ __launch_bounds__(256) void k_prep(const float* __restrict__ rep,
                                              float* __restrict__ ws) {
    const int w = threadIdx.x >> 6, l = threadIdx.x & 63;
    const int wg = blockIdx.x * 4 + w;          // 0..1023
    __bf16* nbf = (__bf16*)(ws + WS_NBF);
    float zacc = 0.f, pacc = 0.f;
    #pragma unroll
    for (int p = 0; p < 4; ++p) {
        const int i = wg + p * 1024;            // 0..4095
        float2 a = *reinterpret_cast<const float2*>(rep + i * D + l * 2);
        float2 b = *reinterpret_cast<const float2*>(rep + (i + BATCH) * D + l * 2);
        float dx = a.x - b.x, dy = a.y - b.y;
        float sa  = wave_reduce(a.x * a.x + a.y * a.y);
        float sb  = wave_reduce(b.x * b.x + b.y * b.y);
        float sab = wave_reduce(a.x * b.x + a.y * b.y);
        float sd  = wave_reduce(dx * dx + dy * dy);
        float ia = 1.0f / (sqrtf(sa) + 1e-8f);
        float ib = 1.0f / (sqrtf(sb) + 1e-8f);
        zacc += sd;
        pacc += sab * ia * ib;
        bf16x2 pa, pb;
        pa.x = (__bf16)(a.x * ia * SCALE); pa.y = (__bf16)(a.y * ia * SCALE);
        pb.x = (__bf16)(b.x * ib * SCALE); pb.y = (__bf16)(b.y * ib * SCALE);
        *reinterpret_cast<bf16x2*>(nbf + i * D + l * 2) = pa;
        *reinterpret_cast<bf16x2*>(nbf + (i + BATCH) * D + l * 2) = pb;
    }
    __shared__ float shz[4], shp[4];
    if (l == 0) { shz[w] = zacc; shp[w] = pacc; }
    __syncthreads();
    if (threadIdx.x == 0) {
        ws[WS_ZRECP + blockIdx.x] = shz[0] + shz[1] + shz[2] + shz[3];
        ws[WS_POSP + blockIdx.x] = 4.0f * (shp[0] + shp[1] + shp[2] + shp[3]);
    }
}

// Upper-triangle MFMA Gram + fused exp2 row/col sums + fused xrecon-MSE share.
// Block (r,s) owns tiles c in [r+4s, min(r+4s+4, 64)); empty blocks exit after
// writing their recon share and zeroed row-partial slot.
__global__ __launch_bounds__(256, 2) void k_lse(const float4* __restrict__ xr,
                                                const float4* __restrict__ xo,
                                                float* __restrict__ ws) {
    __shared__ __bf16 buf[2][128 * D];           // 2 x 32 KB
    __shared__ float shr[4];
    const __bf16* __restrict__ nbf = (const __bf16*)(ws + WS_NBF);

    const int tid = threadIdx.x;
    const int w = tid >> 6, l = tid & 63;
    const int rblk = blockIdx.x;                 // 0..63
    const int sseg = blockIdx.y;                 // 0..15
    const int c0 = rblk + SEG * sseg;
    const int nt = min(c0 + SEG, NBLK) - c0;     // tiles this block (may be <=0)
    const int fid = rblk * NSEG + sseg;          // 0..1023

    // ---- fused xrecon MSE share (all blocks, fixed deterministic slice)
    float racc = 0.f;
    #pragma unroll
    for (int it = 0; it < 4; ++it) {
        const int idx = fid * 1024 + it * 256 + tid;   // 1024*1024 = 8192*512/4
        float4 ra = xr[idx], rb = xo[idx];
        float dx = ra.x - rb.x, dy = ra.y - rb.y;
        float dz = ra.z - rb.z, dw2 = ra.w - rb.w;
        racc += dx * dx + dy * dy + dz * dz + dw2 * dw2;
    }
    racc = wave_reduce(racc);
    if (l == 0) shr[w] = racc;
    __syncthreads();
    if (tid == 0) ws[WS_RECONP + fid] = shr[0] + shr[1] + shr[2] + shr[3];

    if (nt <= 0) {
        if (tid < 128) ws[WS_RP + fid * 128 + tid] = 0.f;   // never-touched seg
        return;
    }

    // wave w stages rows [w*32, w*32+32) of a 128x128 bf16 tile (linear LDS,
    // pre-swizzled global source chunk)
    auto stage = [&](int bufi, int grow0) {
        #pragma unroll
        for (int q = 0; q < 8; ++q) {
            const int lr = w * 32 + q * 4 + (l >> 4);       // local row 0..127
            const int schunk = (l & 15) ^ (lr & 15);
            const __bf16* src = nbf + (grow0 + lr) * D + schunk * 8;
            gload_lds16(src, &buf[bufi][(w * 32 + q * 4) * D]);
        }
    };

    stage(0, rblk * 128);
    __syncthreads();

    bf16x8 afrag[8];
    {
        const int lr = w * 32 + (l & 31);
        const int xw = lr & 15;
        #pragma unroll
        for (int s = 0; s < 8; ++s) {
            const int c = 2 * s + (l >> 5);
            afrag[s] = *reinterpret_cast<const bf16x8*>(&buf[0][lr * D + (c ^ xw) * 8]);
        }
    }

    stage(1, c0 * 128);          // B tile 0
    __syncthreads();

    float sumexp[16] = {};

    for (int t = 0; t < nt; ++t) {
        const int c = c0 + t;
        const int cur = 1 - (t & 1);
        if (t + 1 < nt) stage(t & 1, (c + 1) * 128);

        f32x16 acc[4] = {};
        const __bf16* bb = &buf[cur][0];
        const int xl = l & 15;
        #pragma unroll
        for (int s = 0; s < 8; ++s) {
            const int cc = 2 * s + (l >> 5);
            #pragma unroll
            for (int cb = 0; cb < 4; ++cb) {
                const int lc = cb * 32 + (l & 31);
                bf16x8 bfr = *reinterpret_cast<const bf16x8*>(
                    &bb[lc * D + (cc ^ xl) * 8]);
                acc[cb] = __builtin_amdgcn_mfma_f32_32x32x16_bf16(
                    afrag[s], bfr, acc[cb], 0, 0, 0);
            }
        }

        if (c == rblk) {
            // diagonal tile: rows only, mask the diagonal element
            #pragma unroll
            for (int cb = 0; cb < 4; ++cb) {
                #pragma unroll
                for (int r = 0; r < 16; ++r) {
                    float e = __builtin_amdgcn_exp2f(acc[cb][r]);
                    if (cb == w) {
                        const int rrow = (r & 3) + 8 * (r >> 2) + 4 * (l >> 5);
                        if (rrow == (l & 31)) e = 0.0f;
                    }
                    sumexp[r] += e;
                }
            }
        } else {
            // off-diagonal: rows AND per-wave column partials
            float colacc[4] = {0.f, 0.f, 0.f, 0.f};
            #pragma unroll
            for (int cb = 0; cb < 4; ++cb) {
                #pragma unroll
                for (int r = 0; r < 16; ++r) {
                    float e = __builtin_amdgcn_exp2f(acc[cb][r]);
                    sumexp[r] += e;
                    colacc[cb] += e;
                }
                colacc[cb] += __shfl_xor(colacc[cb], 32);  // combine row halves
            }
            if (l < 32) {
                float* cp = ws + WS_CP + ((c * NBLK + rblk) * 4 + w) * 128 + l;
                #pragma unroll
                for (int cb = 0; cb < 4; ++cb) cp[cb * 32] = colacc[cb];
            }
        }
        __syncthreads();
    }

    // row partials: reduce the 32 column-lanes; lanes 0 and 32 hold row sums
    #pragma unroll
    for (int r = 0; r < 16; ++r) {
        float v = sumexp[r];
        #pragma unroll
        for (int m = 1; m <= 16; m <<= 1) v += __shfl_xor(v, m);
        sumexp[r] = v;
    }
    if ((l & 31) == 0) {
        #pragma unroll
        for (int r = 0; r < 16; ++r) {
            const int j = w * 32 + (r & 3) + 8 * (r >> 2) + 4 * (l >> 5);
            ws[WS_RP + fid * 128 + j] = sumexp[r];
        }
    }
}

// per row-block q: rowsum = 16 RP segs + 4*q CP slots; then log + block partial
__global__ __launch_bounds__(256) void k_rowlse(float* __restrict__ ws) {
    const int q = blockIdx.x, tid = threadIdx.x;
    const int j = tid & 127, h = tid >> 7;       // 2 threads per row
    float s = 0.f;
    for (int ss = h; ss < NSEG; ss += 2)
        s += ws[WS_RP + (q * NSEG + ss) * 128 + j];
    const float* cpb = ws + WS_CP + q * NBLK * 4 * 128;
    for (int v = h; v < q * 4; v += 2)
        s += cpb[v * 128 + j];
    __shared__ float red[128];
    if (h) red[j] = s;
    __syncthreads();
    float lg = 0.f;
    if (!h) lg = logf(s + red[j]);
    lg = wave_reduce(lg);
    __shared__ float sh[4];
    const int w = tid >> 6, l = tid & 63;
    if (l == 0) sh[w] = lg;
    __syncthreads();
    if (tid == 0) ws[WS_LSEP + q] = sh[0] + sh[1] + sh[2] + sh[3];
}

__global__ __launch_bounds__(256) void k_combine(const float* __restrict__ ws,
                                                 float* __restrict__ out) {
    const int tid = threadIdx.x;
    float lacc = (tid < 64) ? ws[WS_LSEP + tid] : 0.f;
    float racc = ws[WS_RECONP + tid] + ws[WS_RECONP + 256 + tid]
               + ws[WS_RECONP + 512 + tid] + ws[WS_RECONP + 768 + tid];
    float zacc = ws[WS_ZRECP + tid];
    float pacc = ws[WS_POSP + tid];

    lacc = wave_reduce(lacc);
    racc = wave_reduce(racc);
    zacc = wave_reduce(zacc);
    pacc = wave_reduce(pacc);

    __shared__ float sh[4][4];
    const int w = tid >> 6, l = tid & 63;
    if (l == 0) { sh[0][w] = lacc; sh[1][w] = racc; sh[2][w] = zacc; sh[3][w] = pacc; }
    __syncthreads();
    if (tid == 0) {
        float lse = sh[0][0] + sh[0][1] + sh[0][2] + sh[0][3];
        float rec = (sh[1][0] + sh[1][1] + sh[1][2] + sh[1][3]) / (float)(NROWS * DX);
        float zre = (sh[2][0] + sh[2][1] + sh[2][2] + sh[2][3]) / (float)(BATCH * D);
        float pos = sh[3][0] + sh[3][1] + sh[3][2] + sh[3][3];
        float closs = (lse - pos) / (float)NROWS;
        out[0] = rec + closs + zre;
        out[1] = closs;
        out[2] = rec;
        out[3] = zre;
    }
}

extern "C" void kernel_launch(void* const* d_in, const int* in_sizes, int n_in,
                              void* d_out, int out_size, void* d_ws, size_t ws_size,
                              hipStream_t stream) {
    const float* rep = (const float*)d_in[0];
    const float4* xr = (const float4*)d_in[1];
    const float4* xo = (const float4*)d_in[2];
    float* out = (float*)d_out;
    float* ws = (float*)d_ws;

    k_prep<<<256, 256, 0, stream>>>(rep, ws);
    dim3 grid(NBLK, NSEG);
    k_lse<<<grid, 256, 0, stream>>>(xr, xo, ws);
    k_rowlse<<<NBLK, 256, 0, stream>>>(ws);
    k_combine<<<1, 256, 0, stream>>>(ws, out);
}

// Round 5
// 59.299 us; speedup vs baseline: 1.2420x; 1.2420x over previous
//
#include <hip/hip_runtime.h>
#include <math.h>

#define BATCH 4096
#define NROWS (2 * BATCH)      // 8192
#define D 128
#define DX 512

constexpr int NSPLIT = 8;
constexpr int NT = 8;          // 128-col tiles per split (1024 cols)

// sqrt(2*log2(e)) — both Gram operands carry this, so dot == log2(exp(sim))
#define SCALE 1.698644f

// ws float offsets (every slot that is read is written every call; no atomics)
#define WS_PART   0                          // [NROWS][NSPLIT]
#define WS_RECONP 65536                      // [512]
#define WS_ZRECP  (WS_RECONP + 512)          // [256]
#define WS_POSP   (WS_ZRECP + 256)           // [256]
#define WS_NBFT   (WS_POSP + 256)            // bf16[16][NROWS][8] chunk-transposed

typedef __bf16 bf16x8 __attribute__((ext_vector_type(8)));
typedef __bf16 bf16x2 __attribute__((ext_vector_type(2)));
typedef float  f32x16 __attribute__((ext_vector_type(16)));

__device__ __forceinline__ float wave_reduce(float v) {
    #pragma unroll
    for (int o = 32; o > 0; o >>= 1) v += __shfl_xor(v, o);
    return v;
}

// one wave per (i, i+B) pair: norms, chunk-transposed scaled-bf16 rows,
// zrecon & positives partials
__global__ __launch_bounds__(256) void k_prep(const float* __restrict__ rep,
                                              float* __restrict__ ws) {
    const int w = threadIdx.x >> 6, l = threadIdx.x & 63;
    const int wg = blockIdx.x * 4 + w;          // 0..1023
    __bf16* nbfT = (__bf16*)(ws + WS_NBFT);
    const int chunk = l >> 2, el = (l & 3) * 2; // lane's 2 elems live here
    float zacc = 0.f, pacc = 0.f;
    #pragma unroll
    for (int p = 0; p < 4; ++p) {
        const int i = wg + p * 1024;            // 0..4095
        float2 a = *reinterpret_cast<const float2*>(rep + i * D + l * 2);
        float2 b = *reinterpret_cast<const float2*>(rep + (i + BATCH) * D + l * 2);
        float dx = a.x - b.x, dy = a.y - b.y;
        float sa  = wave_reduce(a.x * a.x + a.y * a.y);
        float sb  = wave_reduce(b.x * b.x + b.y * b.y);
        float sab = wave_reduce(a.x * b.x + a.y * b.y);
        float sd  = wave_reduce(dx * dx + dy * dy);
        float ia = 1.0f / (sqrtf(sa) + 1e-8f);
        float ib = 1.0f / (sqrtf(sb) + 1e-8f);
        zacc += sd;
        pacc += sab * ia * ib;
        bf16x2 pa, pb;
        pa.x = (__bf16)(a.x * ia * SCALE); pa.y = (__bf16)(a.y * ia * SCALE);
        pb.x = (__bf16)(b.x * ib * SCALE); pb.y = (__bf16)(b.y * ib * SCALE);
        *reinterpret_cast<bf16x2*>(nbfT + ((size_t)chunk * NROWS + i) * 8 + el) = pa;
        *reinterpret_cast<bf16x2*>(
            nbfT + ((size_t)chunk * NROWS + i + BATCH) * 8 + el) = pb;
    }
    __shared__ float shz[4], shp[4];
    if (l == 0) { shz[w] = zacc; shp[w] = pacc; }
    __syncthreads();
    if (threadIdx.x == 0) {
        ws[WS_ZRECP + blockIdx.x] = shz[0] + shz[1] + shz[2] + shz[3];
        ws[WS_POSP + blockIdx.x] = 4.0f * (shp[0] + shp[1] + shp[2] + shp[3]);
    }
}

// MFMA Gram + fused exp2-rowsum + fused xrecon-MSE partial.
// NO LDS, NO barriers in the main loop: A and B fragments load straight from
// the L2-resident chunk-transposed copy; coalesced (two 512B segments/instr).
__global__ __launch_bounds__(256, 2) void k_lse(const float4* __restrict__ xr,
                                                const float4* __restrict__ xo,
                                                float* __restrict__ ws) {
    const __bf16* __restrict__ nbfT = (const __bf16*)(ws + WS_NBFT);
    const int tid = threadIdx.x;
    const int w = tid >> 6, l = tid & 63;
    const int rblk = blockIdx.x;                 // 0..63
    const int split = blockIdx.y;                // 0..7
    const int R0 = rblk * 128;
    const int fid = rblk + 64 * split;           // 0..511

    // ---- A fragments (registers, reused across all 8 tiles)
    bf16x8 afrag[8];
    {
        const int lr = R0 + w * 32 + (l & 31);
        #pragma unroll
        for (int s = 0; s < 8; ++s) {
            const int c = 2 * s + (l >> 5);
            afrag[s] = *reinterpret_cast<const bf16x8*>(
                nbfT + ((size_t)c * NROWS + lr) * 8);
        }
    }

    float sumexp[16] = {};
    float racc = 0.f;

    for (int t = 0; t < NT; ++t) {
        const int C0 = split * (NT * 128) + t * 128;

        // fused xrecon MSE: one float4-pair per thread per tile
        const int ridx = fid * 2048 + t * 256 + tid;
        float4 ra = xr[ridx], rb = xo[ridx];

        f32x16 acc[4] = {};
        #pragma unroll
        for (int cb = 0; cb < 4; ++cb) {
            const int lc = C0 + cb * 32 + (l & 31);
            #pragma unroll
            for (int s = 0; s < 8; ++s) {
                const int c = 2 * s + (l >> 5);
                bf16x8 bfr = *reinterpret_cast<const bf16x8*>(
                    nbfT + ((size_t)c * NROWS + lc) * 8);
                acc[cb] = __builtin_amdgcn_mfma_f32_32x32x16_bf16(
                    afrag[s], bfr, acc[cb], 0, 0, 0);
            }
        }

        // acc == sim*log2(e) by operand scaling → exp(sim) = exp2(acc)
        const bool diag = (C0 == R0);
        #pragma unroll
        for (int cb = 0; cb < 4; ++cb) {
            #pragma unroll
            for (int r = 0; r < 16; ++r) {
                float e = __builtin_amdgcn_exp2f(acc[cb][r]);
                if (diag && cb == w) {
                    const int rrow = (r & 3) + 8 * (r >> 2) + 4 * (l >> 5);
                    if (rrow == (l & 31)) e = 0.0f;
                }
                sumexp[r] += e;
            }
        }

        {
            float dx = ra.x - rb.x, dy = ra.y - rb.y;
            float dz = ra.z - rb.z, dw2 = ra.w - rb.w;
            racc += dx * dx + dy * dy + dz * dz + dw2 * dw2;
        }
    }

    // reduce the 32 column-lanes; lanes 0 and 32 hold row sums
    #pragma unroll
    for (int r = 0; r < 16; ++r) {
        float v = sumexp[r];
        #pragma unroll
        for (int m = 1; m <= 16; m <<= 1) v += __shfl_xor(v, m);
        sumexp[r] = v;
    }
    if ((l & 31) == 0) {
        #pragma unroll
        for (int r = 0; r < 16; ++r) {
            const int row = R0 + w * 32 + (r & 3) + 8 * (r >> 2) + 4 * (l >> 5);
            ws[WS_PART + row * NSPLIT + split] = sumexp[r];
        }
    }

    // recon partial for this block
    racc = wave_reduce(racc);
    __shared__ float shr[4];
    if (l == 0) shr[w] = racc;
    __syncthreads();
    if (tid == 0) ws[WS_RECONP + fid] = shr[0] + shr[1] + shr[2] + shr[3];
}

// single block: per-row log of summed split-partials + final combine
__global__ __launch_bounds__(256) void k_combine(const float* __restrict__ ws,
                                                 float* __restrict__ out) {
    const int tid = threadIdx.x;
    float lacc = 0.f;
    for (int i = tid; i < NROWS; i += 256) {
        float s = 0.f;
        #pragma unroll
        for (int t = 0; t < NSPLIT; ++t) s += ws[WS_PART + i * NSPLIT + t];
        lacc += logf(s);
    }
    float racc = ws[WS_RECONP + tid] + ws[WS_RECONP + 256 + tid];
    float zacc = ws[WS_ZRECP + tid];
    float pacc = ws[WS_POSP + tid];

    lacc = wave_reduce(lacc);
    racc = wave_reduce(racc);
    zacc = wave_reduce(zacc);
    pacc = wave_reduce(pacc);

    __shared__ float sh[4][4];
    const int w = tid >> 6, l = tid & 63;
    if (l == 0) { sh[0][w] = lacc; sh[1][w] = racc; sh[2][w] = zacc; sh[3][w] = pacc; }
    __syncthreads();
    if (tid == 0) {
        float lse = sh[0][0] + sh[0][1] + sh[0][2] + sh[0][3];
        float rec = (sh[1][0] + sh[1][1] + sh[1][2] + sh[1][3]) / (float)(NROWS * DX);
        float zre = (sh[2][0] + sh[2][1] + sh[2][2] + sh[2][3]) / (float)(BATCH * D);
        float pos = sh[3][0] + sh[3][1] + sh[3][2] + sh[3][3];
        float closs = (lse - pos) / (float)NROWS;
        out[0] = rec + closs + zre;
        out[1] = closs;
        out[2] = rec;
        out[3] = zre;
    }
}

extern "C" void kernel_launch(void* const* d_in, const int* in_sizes, int n_in,
                              void* d_out, int out_size, void* d_ws, size_t ws_size,
                              hipStream_t stream) {
    const float* rep = (const float*)d_in[0];
    const float4* xr = (const float4*)d_in[1];
    const float4* xo = (const float4*)d_in[2];
    float* out = (float*)d_out;
    float* ws = (float*)d_ws;

    k_prep<<<256, 256, 0, stream>>>(rep, ws);
    dim3 grid(64, NSPLIT);
    k_lse<<<grid, 256, 0, stream>>>(xr, xo, ws);
    k_combine<<<1, 256, 0, stream>>>(ws, out);
}

// Round 6
// 41.715 us; speedup vs baseline: 1.7656x; 1.4215x over previous
//
#include <hip/hip_runtime.h>
#include <math.h>

#define BATCH 4096
#define NROWS (2 * BATCH)      // 8192
#define D 128
#define DX 512

constexpr int NSPLIT = 8;
constexpr int NT = 8;          // 128-col tiles per split (1024 cols)
constexpr int SLOTS = NSPLIT * 2;   // row-partial slots (split x wc)

// sqrt(2*log2(e)) — both Gram operands carry this, so dot == log2(exp(sim))
#define SCALE 1.698644f

// ws float offsets (every slot that is read is written every call; no atomics)
#define WS_PART   0                          // [NROWS][SLOTS]
#define WS_RECONP 131072                     // [512]
#define WS_ZRECP  (WS_RECONP + 512)          // [256]
#define WS_POSP   (WS_ZRECP + 256)           // [256]
#define WS_LSEP   (WS_POSP + 256)            // [64]
#define WS_NBFT   (WS_LSEP + 64)             // bf16[16][NROWS][8] chunk-transposed

typedef __bf16 bf16x8 __attribute__((ext_vector_type(8)));
typedef __bf16 bf16x2 __attribute__((ext_vector_type(2)));
typedef float  f32x16 __attribute__((ext_vector_type(16)));

__device__ __forceinline__ float wave_reduce(float v) {
    #pragma unroll
    for (int o = 32; o > 0; o >>= 1) v += __shfl_xor(v, o);
    return v;
}

// one wave per (i, i+B) pair: norms, chunk-transposed scaled-bf16 rows,
// zrecon & positives partials
__global__ __launch_bounds__(256) void k_prep(const float* __restrict__ rep,
                                              float* __restrict__ ws) {
    const int w = threadIdx.x >> 6, l = threadIdx.x & 63;
    const int wg = blockIdx.x * 4 + w;          // 0..1023
    __bf16* nbfT = (__bf16*)(ws + WS_NBFT);
    const int chunk = l >> 2, el = (l & 3) * 2; // lane's 2 elems live here
    float zacc = 0.f, pacc = 0.f;
    #pragma unroll
    for (int p = 0; p < 4; ++p) {
        const int i = wg + p * 1024;            // 0..4095
        float2 a = *reinterpret_cast<const float2*>(rep + i * D + l * 2);
        float2 b = *reinterpret_cast<const float2*>(rep + (i + BATCH) * D + l * 2);
        float dx = a.x - b.x, dy = a.y - b.y;
        float sa  = wave_reduce(a.x * a.x + a.y * a.y);
        float sb  = wave_reduce(b.x * b.x + b.y * b.y);
        float sab = wave_reduce(a.x * b.x + a.y * b.y);
        float sd  = wave_reduce(dx * dx + dy * dy);
        float ia = 1.0f / (sqrtf(sa) + 1e-8f);
        float ib = 1.0f / (sqrtf(sb) + 1e-8f);
        zacc += sd;
        pacc += sab * ia * ib;
        bf16x2 pa, pb;
        pa.x = (__bf16)(a.x * ia * SCALE); pa.y = (__bf16)(a.y * ia * SCALE);
        pb.x = (__bf16)(b.x * ib * SCALE); pb.y = (__bf16)(b.y * ib * SCALE);
        *reinterpret_cast<bf16x2*>(nbfT + ((size_t)chunk * NROWS + i) * 8 + el) = pa;
        *reinterpret_cast<bf16x2*>(
            nbfT + ((size_t)chunk * NROWS + i + BATCH) * 8 + el) = pb;
    }
    __shared__ float shz[4], shp[4];
    if (l == 0) { shz[w] = zacc; shp[w] = pacc; }
    __syncthreads();
    if (threadIdx.x == 0) {
        ws[WS_ZRECP + blockIdx.x] = shz[0] + shz[1] + shz[2] + shz[3];
        ws[WS_POSP + blockIdx.x] = 4.0f * (shp[0] + shp[1] + shp[2] + shp[3]);
    }
}

// MFMA Gram + fused exp2-rowsum + fused xrecon-MSE partial.
// No LDS / no barriers in the main loop. 2x2 waves per 128x128 tile; each
// wave owns a 64x64 quadrant, so every B fragment feeds 2 MFMAs (halved
// fragment traffic vs 32x128-per-wave).
__global__ __launch_bounds__(256, 2) void k_lse(const float4* __restrict__ xr,
                                                const float4* __restrict__ xo,
                                                float* __restrict__ ws) {
    const __bf16* __restrict__ nbfT = (const __bf16*)(ws + WS_NBFT);
    const int tid = threadIdx.x;
    const int w = tid >> 6, l = tid & 63;
    const int wr = w >> 1, wc = w & 1;
    const int rblk = blockIdx.x;                 // 0..63
    const int split = blockIdx.y;                // 0..7
    const int R0 = rblk * 128;
    const int fid = rblk + 64 * split;           // 0..511

    // ---- A fragments: 2 row-blocks of 32, registers, reused across tiles
    bf16x8 afrag[2][8];
    #pragma unroll
    for (int rb = 0; rb < 2; ++rb) {
        const int lr = R0 + wr * 64 + rb * 32 + (l & 31);
        #pragma unroll
        for (int s = 0; s < 8; ++s) {
            const int c = 2 * s + (l >> 5);
            afrag[rb][s] = *reinterpret_cast<const bf16x8*>(
                nbfT + ((size_t)c * NROWS + lr) * 8);
        }
    }

    float sumexp[2][16] = {};
    float racc = 0.f;

    for (int t = 0; t < NT; ++t) {
        const int C0 = split * (NT * 128) + t * 128;

        // fused xrecon MSE: one float4-pair per thread per tile
        const int ridx = fid * 2048 + t * 256 + tid;
        float4 ra = xr[ridx], rbv = xo[ridx];

        f32x16 acc[2][2] = {};
        #pragma unroll
        for (int s = 0; s < 8; ++s) {
            const int c = 2 * s + (l >> 5);
            const __bf16* base = nbfT + (size_t)c * NROWS * 8;
            const int lc = C0 + wc * 64 + (l & 31);
            bf16x8 b0 = *reinterpret_cast<const bf16x8*>(base + (size_t)lc * 8);
            bf16x8 b1 = *reinterpret_cast<const bf16x8*>(base + (size_t)(lc + 32) * 8);
            acc[0][0] = __builtin_amdgcn_mfma_f32_32x32x16_bf16(
                afrag[0][s], b0, acc[0][0], 0, 0, 0);
            acc[0][1] = __builtin_amdgcn_mfma_f32_32x32x16_bf16(
                afrag[0][s], b1, acc[0][1], 0, 0, 0);
            acc[1][0] = __builtin_amdgcn_mfma_f32_32x32x16_bf16(
                afrag[1][s], b0, acc[1][0], 0, 0, 0);
            acc[1][1] = __builtin_amdgcn_mfma_f32_32x32x16_bf16(
                afrag[1][s], b1, acc[1][1], 0, 0, 0);
        }

        // acc == sim*log2(e) by operand scaling → exp(sim) = exp2(acc)
        const bool diagt = (C0 == R0);
        #pragma unroll
        for (int rb = 0; rb < 2; ++rb) {
            #pragma unroll
            for (int cb = 0; cb < 2; ++cb) {
                const bool dmask = diagt && (2 * wr + rb) == (2 * wc + cb);
                #pragma unroll
                for (int r = 0; r < 16; ++r) {
                    float e = __builtin_amdgcn_exp2f(acc[rb][cb][r]);
                    if (dmask) {
                        const int rrow = (r & 3) + 8 * (r >> 2) + 4 * (l >> 5);
                        if (rrow == (l & 31)) e = 0.0f;
                    }
                    sumexp[rb][r] += e;
                }
            }
        }

        {
            float dx = ra.x - rbv.x, dy = ra.y - rbv.y;
            float dz = ra.z - rbv.z, dw2 = ra.w - rbv.w;
            racc += dx * dx + dy * dy + dz * dz + dw2 * dw2;
        }
    }

    // reduce over the 32 column-lanes; lanes 0 and 32 hold row sums
    #pragma unroll
    for (int rb = 0; rb < 2; ++rb) {
        #pragma unroll
        for (int r = 0; r < 16; ++r) {
            float v = sumexp[rb][r];
            #pragma unroll
            for (int m = 1; m <= 16; m <<= 1) v += __shfl_xor(v, m);
            sumexp[rb][r] = v;
        }
    }
    if ((l & 31) == 0) {
        #pragma unroll
        for (int rb = 0; rb < 2; ++rb) {
            #pragma unroll
            for (int r = 0; r < 16; ++r) {
                const int row = R0 + wr * 64 + rb * 32
                              + (r & 3) + 8 * (r >> 2) + 4 * (l >> 5);
                ws[WS_PART + row * SLOTS + split * 2 + wc] = sumexp[rb][r];
            }
        }
    }

    // recon partial for this block
    racc = wave_reduce(racc);
    __shared__ float shr[4];
    if (l == 0) shr[w] = racc;
    __syncthreads();
    if (tid == 0) ws[WS_RECONP + fid] = shr[0] + shr[1] + shr[2] + shr[3];
}

// per row-block q (128 rows): sum the 16 slots per row, log, block partial
__global__ __launch_bounds__(256) void k_rowlse(float* __restrict__ ws) {
    const int q = blockIdx.x, tid = threadIdx.x;
    const int j = tid & 127, h = tid >> 7;       // 2 threads per row
    const int row = q * 128 + j;
    float s = 0.f;
    #pragma unroll
    for (int ss = 0; ss < SLOTS / 2; ++ss)
        s += ws[WS_PART + row * SLOTS + 2 * ss + h];
    __shared__ float red[128];
    if (h) red[j] = s;
    __syncthreads();
    float lg = 0.f;
    if (!h) lg = logf(s + red[j]);
    lg = wave_reduce(lg);
    __shared__ float sh[4];
    const int w = tid >> 6, l = tid & 63;
    if (l == 0) sh[w] = lg;
    __syncthreads();
    if (tid == 0) ws[WS_LSEP + q] = sh[0] + sh[1] + sh[2] + sh[3];
}

__global__ __launch_bounds__(256) void k_combine(const float* __restrict__ ws,
                                                 float* __restrict__ out) {
    const int tid = threadIdx.x;
    float lacc = (tid < 64) ? ws[WS_LSEP + tid] : 0.f;
    float racc = ws[WS_RECONP + tid] + ws[WS_RECONP + 256 + tid];
    float zacc = ws[WS_ZRECP + tid];
    float pacc = ws[WS_POSP + tid];

    lacc = wave_reduce(lacc);
    racc = wave_reduce(racc);
    zacc = wave_reduce(zacc);
    pacc = wave_reduce(pacc);

    __shared__ float sh[4][4];
    const int w = tid >> 6, l = tid & 63;
    if (l == 0) { sh[0][w] = lacc; sh[1][w] = racc; sh[2][w] = zacc; sh[3][w] = pacc; }
    __syncthreads();
    if (tid == 0) {
        float lse = sh[0][0] + sh[0][1] + sh[0][2] + sh[0][3];
        float rec = (sh[1][0] + sh[1][1] + sh[1][2] + sh[1][3]) / (float)(NROWS * DX);
        float zre = (sh[2][0] + sh[2][1] + sh[2][2] + sh[2][3]) / (float)(BATCH * D);
        float pos = sh[3][0] + sh[3][1] + sh[3][2] + sh[3][3];
        float closs = (lse - pos) / (float)NROWS;
        out[0] = rec + closs + zre;
        out[1] = closs;
        out[2] = rec;
        out[3] = zre;
    }
}

extern "C" void kernel_launch(void* const* d_in, const int* in_sizes, int n_in,
                              void* d_out, int out_size, void* d_ws, size_t ws_size,
                              hipStream_t stream) {
    const float* rep = (const float*)d_in[0];
    const float4* xr = (const float4*)d_in[1];
    const float4* xo = (const float4*)d_in[2];
    float* out = (float*)d_out;
    float* ws = (float*)d_ws;

    k_prep<<<256, 256, 0, stream>>>(rep, ws);
    dim3 grid(64, NSPLIT);
    k_lse<<<grid, 256, 0, stream>>>(xr, xo, ws);
    k_rowlse<<<64, 256, 0, stream>>>(ws);
    k_combine<<<1, 256, 0, stream>>>(ws, out);
}

// Round 7
// 37.504 us; speedup vs baseline: 1.9639x; 1.1123x over previous
//
#include <hip/hip_runtime.h>
#include <math.h>

#define BATCH 4096
#define NROWS (2 * BATCH)      // 8192
#define D 128
#define DX 512

constexpr int NSPLIT = 16;
constexpr int NT = 4;               // 128-col tiles per split (512 cols)
constexpr int SLOTS = NSPLIT * 2;   // row-partial slots (split x wc) = 32

// sqrt(2*log2(e)) — both Gram operands carry this, so dot == log2(exp(sim))
#define SCALE 1.698644f

// ws float offsets (every slot that is read is written every call; no atomics)
#define WS_PART   0                          // [NROWS][SLOTS] = 262144
#define WS_RECONP 262144                     // [1024]
#define WS_ZRECP  (WS_RECONP + 1024)         // [256]
#define WS_POSP   (WS_ZRECP + 256)           // [256]
#define WS_LSEP   (WS_POSP + 256)            // [64]
#define WS_NBF8   (WS_LSEP + 64)             // fp8[16][NROWS][8] chunk-transposed (1 MB)

typedef float f32x16 __attribute__((ext_vector_type(16)));
typedef long long i64;
typedef unsigned char u8;
typedef unsigned short u16;

__device__ __forceinline__ float wave_reduce(float v) {
    #pragma unroll
    for (int o = 32; o > 0; o >>= 1) v += __shfl_xor(v, o);
    return v;
}

// one wave per (i, i+B) pair: norms, chunk-transposed scaled-fp8 rows,
// zrecon & positives partials (f32 exact)
__global__ __launch_bounds__(256) void k_prep(const float* __restrict__ rep,
                                              float* __restrict__ ws) {
    const int w = threadIdx.x >> 6, l = threadIdx.x & 63;
    const int wg = blockIdx.x * 4 + w;          // 0..1023
    u8* nbf8 = (u8*)(ws + WS_NBF8);
    const int chunk = l >> 2, el = (l & 3) * 2; // lane's 2 elems live here
    float zacc = 0.f, pacc = 0.f;
    #pragma unroll
    for (int p = 0; p < 4; ++p) {
        const int i = wg + p * 1024;            // 0..4095
        float2 a = *reinterpret_cast<const float2*>(rep + i * D + l * 2);
        float2 b = *reinterpret_cast<const float2*>(rep + (i + BATCH) * D + l * 2);
        float dx = a.x - b.x, dy = a.y - b.y;
        float sa  = wave_reduce(a.x * a.x + a.y * a.y);
        float sb  = wave_reduce(b.x * b.x + b.y * b.y);
        float sab = wave_reduce(a.x * b.x + a.y * b.y);
        float sd  = wave_reduce(dx * dx + dy * dy);
        float ia = 1.0f / (sqrtf(sa) + 1e-8f);
        float ib = 1.0f / (sqrtf(sb) + 1e-8f);
        zacc += sd;
        pacc += sab * ia * ib;
        // pack 2 scaled fp8 e4m3 (RNE, hardware cvt)
        int pka = __builtin_amdgcn_cvt_pk_fp8_f32(a.x * ia * SCALE,
                                                  a.y * ia * SCALE, 0, false);
        int pkb = __builtin_amdgcn_cvt_pk_fp8_f32(b.x * ib * SCALE,
                                                  b.y * ib * SCALE, 0, false);
        *reinterpret_cast<u16*>(
            nbf8 + ((size_t)chunk * NROWS + i) * 8 + el) = (u16)pka;
        *reinterpret_cast<u16*>(
            nbf8 + ((size_t)chunk * NROWS + i + BATCH) * 8 + el) = (u16)pkb;
    }
    __shared__ float shz[4], shp[4];
    if (l == 0) { shz[w] = zacc; shp[w] = pacc; }
    __syncthreads();
    if (threadIdx.x == 0) {
        ws[WS_ZRECP + blockIdx.x] = shz[0] + shz[1] + shz[2] + shz[3];
        ws[WS_POSP + blockIdx.x] = 4.0f * (shp[0] + shp[1] + shp[2] + shp[3]);
    }
}

// fp8 MFMA Gram + fused exp2-rowsum + fused xrecon-MSE partial.
// No LDS / no barriers in the main loop. 2x2 waves per 128x128 tile; each
// wave owns a 64x64 quadrant. fp8 operands halve fragment traffic vs bf16.
// xrecon pair is consumed+reissued AFTER the MFMA loop's B loads so the
// counted vmcnt waits never expose its HBM latency.
__global__ __launch_bounds__(256, 2) void k_lse(const float4* __restrict__ xr,
                                                const float4* __restrict__ xo,
                                                float* __restrict__ ws) {
    const u8* __restrict__ nbf8 = (const u8*)(ws + WS_NBF8);
    const int tid = threadIdx.x;
    const int w = tid >> 6, l = tid & 63;
    const int wr = w >> 1, wc = w & 1;
    const int rblk = blockIdx.x;                 // 0..63
    const int split = blockIdx.y;                // 0..15
    const int R0 = rblk * 128;
    const int fid = rblk + 64 * split;           // 0..1023

    // ---- A fragments: 2 row-blocks of 32, registers, reused across tiles
    i64 afrag[2][8];
    #pragma unroll
    for (int rb = 0; rb < 2; ++rb) {
        const int lr = R0 + wr * 64 + rb * 32 + (l & 31);
        #pragma unroll
        for (int s = 0; s < 8; ++s) {
            const int c = 2 * s + (l >> 5);
            afrag[rb][s] = *reinterpret_cast<const i64*>(
                nbf8 + ((size_t)c * NROWS + lr) * 8);
        }
    }

    // xrecon prologue pair (tile 0)
    int ridx = fid * 1024 + tid;
    float4 ra = xr[ridx], rbv = xo[ridx];

    float sumexp[2][16] = {};
    float racc = 0.f;

    for (int t = 0; t < NT; ++t) {
        const int C0 = split * (NT * 128) + t * 128;

        f32x16 acc[2][2] = {};
        #pragma unroll
        for (int s = 0; s < 8; ++s) {
            const int c = 2 * s + (l >> 5);
            const u8* base = nbf8 + (size_t)c * NROWS * 8;
            const int lc = C0 + wc * 64 + (l & 31);
            i64 b0 = *reinterpret_cast<const i64*>(base + (size_t)lc * 8);
            i64 b1 = *reinterpret_cast<const i64*>(base + (size_t)(lc + 32) * 8);
            acc[0][0] = __builtin_amdgcn_mfma_f32_32x32x16_fp8_fp8(
                afrag[0][s], b0, acc[0][0], 0, 0, 0);
            acc[0][1] = __builtin_amdgcn_mfma_f32_32x32x16_fp8_fp8(
                afrag[0][s], b1, acc[0][1], 0, 0, 0);
            acc[1][0] = __builtin_amdgcn_mfma_f32_32x32x16_fp8_fp8(
                afrag[1][s], b0, acc[1][0], 0, 0, 0);
            acc[1][1] = __builtin_amdgcn_mfma_f32_32x32x16_fp8_fp8(
                afrag[1][s], b1, acc[1][1], 0, 0, 0);
        }

        // consume current xrecon pair, then issue the next one (program order:
        // after this tile's B loads → survives next tile's counted waits)
        {
            float dx = ra.x - rbv.x, dy = ra.y - rbv.y;
            float dz = ra.z - rbv.z, dw2 = ra.w - rbv.w;
            racc += dx * dx + dy * dy + dz * dz + dw2 * dw2;
        }
        if (t + 1 < NT) {
            ridx = fid * 1024 + (t + 1) * 256 + tid;
            ra = xr[ridx];
            rbv = xo[ridx];
        }

        // acc == sim*log2(e) by operand scaling → exp(sim) = exp2(acc)
        const bool diagt = ((C0 >> 7) * 0 == 0) && (C0 - R0 < 128) && (R0 - C0 < 128)
                           && (C0 == R0);
        #pragma unroll
        for (int rb = 0; rb < 2; ++rb) {
            #pragma unroll
            for (int cb = 0; cb < 2; ++cb) {
                const bool dmask = diagt && ((2 * wr + rb) == (2 * wc + cb));
                #pragma unroll
                for (int r = 0; r < 16; ++r) {
                    float e = __builtin_amdgcn_exp2f(acc[rb][cb][r]);
                    if (dmask) {
                        const int rrow = (r & 3) + 8 * (r >> 2) + 4 * (l >> 5);
                        if (rrow == (l & 31)) e = 0.0f;
                    }
                    sumexp[rb][r] += e;
                }
            }
        }
    }

    // reduce over the 32 column-lanes; lanes 0 and 32 hold row sums
    #pragma unroll
    for (int rb = 0; rb < 2; ++rb) {
        #pragma unroll
        for (int r = 0; r < 16; ++r) {
            float v = sumexp[rb][r];
            #pragma unroll
            for (int m = 1; m <= 16; m <<= 1) v += __shfl_xor(v, m);
            sumexp[rb][r] = v;
        }
    }
    if ((l & 31) == 0) {
        #pragma unroll
        for (int rb = 0; rb < 2; ++rb) {
            #pragma unroll
            for (int r = 0; r < 16; ++r) {
                const int row = R0 + wr * 64 + rb * 32
                              + (r & 3) + 8 * (r >> 2) + 4 * (l >> 5);
                ws[WS_PART + row * SLOTS + split * 2 + wc] = sumexp[rb][r];
            }
        }
    }

    // recon partial for this block
    racc = wave_reduce(racc);
    __shared__ float shr[4];
    if (l == 0) shr[w] = racc;
    __syncthreads();
    if (tid == 0) ws[WS_RECONP + fid] = shr[0] + shr[1] + shr[2] + shr[3];
}

// per row-block q (128 rows): sum the 32 slots per row, log, block partial
__global__ __launch_bounds__(256) void k_rowlse(float* __restrict__ ws) {
    const int q = blockIdx.x, tid = threadIdx.x;
    const int j = tid & 127, h = tid >> 7;       // 2 threads per row
    const int row = q * 128 + j;
    float s = 0.f;
    #pragma unroll
    for (int ss = 0; ss < SLOTS / 2; ++ss)
        s += ws[WS_PART + row * SLOTS + 2 * ss + h];
    __shared__ float red[128];
    if (h) red[j] = s;
    __syncthreads();
    float lg = 0.f;
    if (!h) lg = logf(s + red[j]);
    lg = wave_reduce(lg);
    __shared__ float sh[4];
    const int w = tid >> 6, l = tid & 63;
    if (l == 0) sh[w] = lg;
    __syncthreads();
    if (tid == 0) ws[WS_LSEP + q] = sh[0] + sh[1] + sh[2] + sh[3];
}

__global__ __launch_bounds__(256) void k_combine(const float* __restrict__ ws,
                                                 float* __restrict__ out) {
    const int tid = threadIdx.x;
    float lacc = (tid < 64) ? ws[WS_LSEP + tid] : 0.f;
    float racc = ws[WS_RECONP + tid] + ws[WS_RECONP + 256 + tid]
               + ws[WS_RECONP + 512 + tid] + ws[WS_RECONP + 768 + tid];
    float zacc = ws[WS_ZRECP + tid];
    float pacc = ws[WS_POSP + tid];

    lacc = wave_reduce(lacc);
    racc = wave_reduce(racc);
    zacc = wave_reduce(zacc);
    pacc = wave_reduce(pacc);

    __shared__ float sh[4][4];
    const int w = tid >> 6, l = tid & 63;
    if (l == 0) { sh[0][w] = lacc; sh[1][w] = racc; sh[2][w] = zacc; sh[3][w] = pacc; }
    __syncthreads();
    if (tid == 0) {
        float lse = sh[0][0] + sh[0][1] + sh[0][2] + sh[0][3];
        float rec = (sh[1][0] + sh[1][1] + sh[1][2] + sh[1][3]) / (float)(NROWS * DX);
        float zre = (sh[2][0] + sh[2][1] + sh[2][2] + sh[2][3]) / (float)(BATCH * D);
        float pos = sh[3][0] + sh[3][1] + sh[3][2] + sh[3][3];
        float closs = (lse - pos) / (float)NROWS;
        out[0] = rec + closs + zre;
        out[1] = closs;
        out[2] = rec;
        out[3] = zre;
    }
}

extern "C" void kernel_launch(void* const* d_in, const int* in_sizes, int n_in,
                              void* d_out, int out_size, void* d_ws, size_t ws_size,
                              hipStream_t stream) {
    const float* rep = (const float*)d_in[0];
    const float4* xr = (const float4*)d_in[1];
    const float4* xo = (const float4*)d_in[2];
    float* out = (float*)d_out;
    float* ws = (float*)d_ws;

    k_prep<<<256, 256, 0, stream>>>(rep, ws);
    dim3 grid(64, NSPLIT);
    k_lse<<<grid, 256, 0, stream>>>(xr, xo, ws);
    k_rowlse<<<64, 256, 0, stream>>>(ws);
    k_combine<<<1, 256, 0, stream>>>(ws, out);
}